// Round 9
// baseline (466.992 us; speedup 1.0000x reference)
//
#include <hip/hip_runtime.h>
#include <hip/hip_bf16.h>
#include <math.h>

#define L0T 365
#define L1T 366
#define LT  732
#define NTILE 46
#define NW   8
#define NTHR 512
#define PI_F 3.14159265358979323846f

typedef short svec8 __attribute__((ext_vector_type(8)));   // 8 bf16
typedef float fvec4 __attribute__((ext_vector_type(4)));
typedef float fvec16 __attribute__((ext_vector_type(16)));

__device__ __forceinline__ unsigned short f2bf(float f) {
    unsigned u = __float_as_uint(f);
    u = (u + 0x7fffu + ((u >> 16) & 1u)) >> 16;
    return (unsigned short)u;
}
__device__ __forceinline__ float bf2f(unsigned short s) {
    return __uint_as_float(((unsigned)s) << 16);
}
__device__ __forceinline__ unsigned pkcvt(float a, float b) {
    __hip_bfloat162 h = __float22bfloat162_rn(make_float2(a, b));
    union { __hip_bfloat162 h; unsigned u; } c; c.h = h;
    return c.u;
}
__device__ __forceinline__ svec8 pk8(const float* v) {
    union { unsigned u[4]; svec8 s; } r;
    r.u[0] = pkcvt(v[0], v[1]); r.u[1] = pkcvt(v[2], v[3]);
    r.u[2] = pkcvt(v[4], v[5]); r.u[3] = pkcvt(v[6], v[7]);
    return r.s;
}
__device__ __forceinline__ unsigned pk2(float a, float b) { return pkcvt(a, b); }
__device__ __forceinline__ float pget(const unsigned* p, int j) {
    unsigned u = p[j >> 1];
    return bf2f((unsigned short)((j & 1) ? (u >> 16) : (u & 0xffff)));
}

// Token-tile-major swizzled X: tile t (16 tok x 32 feat, 1 KB), u16 index:
//   XSIDX(t,lt,f) = t*512 + lt*32 + ((f>>3) ^ ((lt>>1)&3))*8 + (f&7)
// -> embed write & pipeline read = one 16B op per lane, bank-minimal;
//    Gram scalar reads conflict-free.
#define XSIDX(t, lt, f) \
    (((t) << 9) + ((lt) << 5) + (((((f) >> 3) ^ (((lt) >> 1) & 3)) << 3) | ((f) & 7)))

__global__ __launch_bounds__(NTHR, 4) void fused_kernel(
    const float* __restrict__ x0,  const float* __restrict__ x1,
    const float* __restrict__ pos0,const float* __restrict__ pos1,
    const float* __restrict__ xcT,
    const float* __restrict__ e0w1,const float* __restrict__ e0b1,
    const float* __restrict__ e0w2,const float* __restrict__ e0b2,
    const float* __restrict__ e1w1,const float* __restrict__ e1b1,
    const float* __restrict__ e1w2,const float* __restrict__ e1b2,
    const float* __restrict__ ecw1,const float* __restrict__ ecb1,
    const float* __restrict__ ecw2,const float* __restrict__ ecb2,
    const float* __restrict__ wq,  const float* __restrict__ wk,
    const float* __restrict__ wv,  const float* __restrict__ wo,
    const float* __restrict__ ln1g,const float* __restrict__ ln1b,
    const float* __restrict__ ln2g,const float* __restrict__ ln2b,
    const float* __restrict__ f1w1,const float* __restrict__ f1b1,
    const float* __restrict__ f1w2,const float* __restrict__ f1b2,
    const float* __restrict__ f2w1,const float* __restrict__ f2b1,
    const float* __restrict__ f2w2,const float* __restrict__ f2b2,
    float* __restrict__ out)
{
    const int b   = blockIdx.x;
    const int tid = threadIdx.x;
    const int w   = tid >> 6;          // wave 0..7
    const int ln  = tid & 63;
    const int tk  = ln & 15;           // token-in-tile / A-row slot
    const int Q   = ln >> 4;           // k-octet / C-row quad
    // permutation trick: A-slot tk holds logical weight rows Lr0 / Lr0+4
    const int Lr0 = ((tk >> 2) * 8) + (tk & 3);
    const int Lr1 = Lr0 + 4;

    __shared__ unsigned short XS[NTILE * 512] __attribute__((aligned(16))); // 47104 B
    __shared__ float Cm[1024];
    __shared__ float T1f[1024];
    __shared__ float T2f[1024];
    __shared__ unsigned short Wbb[1024] __attribute__((aligned(16)));
    __shared__ float red[NW * 3];

    // zero Gram accumulator + pad tokens 732..735 (tile 45, lt 12..15)
    for (int i = tid; i < 1024; i += NTHR) Cm[i] = 0.f;
    if (tid < 128) {
        int lt = 12 + (tid >> 5), f = tid & 31;
        XS[XSIDX(45, lt, f)] = 0;
    }

    // posenc angular freqs for this lane's feats Q*8+j
    float pw[8];
    #pragma unroll
    for (int j = 0; j < 8; j++) pw[j] = PI_F / (float)(Q * 4 + (j >> 1) + 1);

    const fvec4 zc = {0.f, 0.f, 0.f, 0.f};

    // =================== EMBED =====================
    // ---- e0 (tiles 0..22, valid tok < 365) ----
    {
        svec8 w1f0, w1f1, w2f0, w2f1;
        float hb8[8], xb8[8];
        #pragma unroll
        for (int j = 0; j < 8; j++) {
            w1f0[j] = (Q == 0) ? (short)f2bf(e0w1[Lr0 * 8 + j]) : (short)0;
            w1f1[j] = (Q == 0) ? (short)f2bf(e0w1[Lr1 * 8 + j]) : (short)0;
            w2f0[j] = (short)f2bf(e0w2[Lr0 * 32 + Q * 8 + j]);
            w2f1[j] = (short)f2bf(e0w2[Lr1 * 32 + Q * 8 + j]);
            hb8[j]  = e0b1[Q * 8 + j];
            xb8[j]  = e0b2[Q * 8 + j];
        }
        for (int t = w; t <= 22; t += NW) {
            const int tok = t * 16 + tk;
            const bool valid = (tok < L0T);
            svec8 bx;
            #pragma unroll
            for (int j = 0; j < 8; j++) bx[j] = 0;
            if (Q == 0 && valid) {
                const float4* px = (const float4*)(x0 + ((size_t)b * L0T + tok) * 8);
                float4 a = px[0], c = px[1];
                float iv[8] = {a.x,a.y,a.z,a.w,c.x,c.y,c.z,c.w};
                bx = pk8(iv);
            }
            float pv = valid ? pos0[(size_t)b * L0T + tok] : 0.f;
            fvec4 d0 = __builtin_amdgcn_mfma_f32_16x16x32_bf16(w1f0, bx, zc, 0,0,0);
            fvec4 d1 = __builtin_amdgcn_mfma_f32_16x16x32_bf16(w1f1, bx, zc, 0,0,0);
            float hv[8];
            #pragma unroll
            for (int j = 0; j < 4; j++) {
                hv[j]   = fmaxf(d0[j] + hb8[j], 0.f);
                hv[4+j] = fmaxf(d1[j] + hb8[4+j], 0.f);
            }
            svec8 hf = pk8(hv);
            fvec4 g0 = __builtin_amdgcn_mfma_f32_16x16x32_bf16(w2f0, hf, zc, 0,0,0);
            fvec4 g1 = __builtin_amdgcn_mfma_f32_16x16x32_bf16(w2f1, hf, zc, 0,0,0);
            if (valid) {
                float xv[8];
                #pragma unroll
                for (int j = 0; j < 8; j++) {
                    float ang = pv * pw[j];
                    xv[j] = (j < 4 ? g0[j] : g1[j - 4]) + xb8[j]
                          + ((j & 1) ? __cosf(ang) : __sinf(ang));
                }
                *(svec8*)&XS[XSIDX(t, tk, Q * 8)] = pk8(xv);
            }
        }
    }
    // ---- e1 (tiles 22..45, valid 365 <= tok <= 730) ----
    {
        svec8 w1f0, w1f1, w2f0, w2f1;
        float hb8[8], xb8[8];
        #pragma unroll
        for (int j = 0; j < 8; j++) {
            w1f0[j] = (Q < 2) ? (short)f2bf(e1w1[Lr0 * 16 + Q * 8 + j]) : (short)0;
            w1f1[j] = (Q < 2) ? (short)f2bf(e1w1[Lr1 * 16 + Q * 8 + j]) : (short)0;
            w2f0[j] = (short)f2bf(e1w2[Lr0 * 32 + Q * 8 + j]);
            w2f1[j] = (short)f2bf(e1w2[Lr1 * 32 + Q * 8 + j]);
            hb8[j]  = e1b1[Q * 8 + j];
            xb8[j]  = e1b2[Q * 8 + j];
        }
        for (int t = 22 + w; t <= 45; t += NW) {
            const int tok = t * 16 + tk;
            const bool valid = (tok >= L0T && tok <= LT - 2);
            svec8 bx;
            #pragma unroll
            for (int j = 0; j < 8; j++) bx[j] = 0;
            if (Q < 2 && valid) {
                const float4* px = (const float4*)(x1 + ((size_t)b * L1T + (tok - L0T)) * 16 + Q * 8);
                float4 a = px[0], c = px[1];
                float iv[8] = {a.x,a.y,a.z,a.w,c.x,c.y,c.z,c.w};
                bx = pk8(iv);
            }
            float pv = valid ? pos1[(size_t)b * L1T + (tok - L0T)] : 0.f;
            fvec4 d0 = __builtin_amdgcn_mfma_f32_16x16x32_bf16(w1f0, bx, zc, 0,0,0);
            fvec4 d1 = __builtin_amdgcn_mfma_f32_16x16x32_bf16(w1f1, bx, zc, 0,0,0);
            float hv[8];
            #pragma unroll
            for (int j = 0; j < 4; j++) {
                hv[j]   = fmaxf(d0[j] + hb8[j], 0.f);
                hv[4+j] = fmaxf(d1[j] + hb8[4+j], 0.f);
            }
            svec8 hf = pk8(hv);
            fvec4 g0 = __builtin_amdgcn_mfma_f32_16x16x32_bf16(w2f0, hf, zc, 0,0,0);
            fvec4 g1 = __builtin_amdgcn_mfma_f32_16x16x32_bf16(w2f1, hf, zc, 0,0,0);
            if (valid) {
                float xv[8];
                #pragma unroll
                for (int j = 0; j < 8; j++) {
                    float ang = pv * pw[j];
                    xv[j] = (j < 4 ? g0[j] : g1[j - 4]) + xb8[j]
                          + ((j & 1) ? __cosf(ang) : __sinf(ang));
                }
                *(svec8*)&XS[XSIDX(t, tk, Q * 8)] = pk8(xv);
            }
        }
    }
    // ---- ec (token 731 = tile 45, tk 11; no posenc) ----
    if (w == 7) {
        svec8 w1f0, w1f1, w2f0, w2f1;
        float hb8[8], xb8[8];
        #pragma unroll
        for (int j = 0; j < 8; j++) {
            w1f0[j] = (short)f2bf(ecw1[Lr0 * 32 + Q * 8 + j]);
            w1f1[j] = (short)f2bf(ecw1[Lr1 * 32 + Q * 8 + j]);
            w2f0[j] = (short)f2bf(ecw2[Lr0 * 32 + Q * 8 + j]);
            w2f1[j] = (short)f2bf(ecw2[Lr1 * 32 + Q * 8 + j]);
            hb8[j]  = ecb1[Q * 8 + j];
            xb8[j]  = ecb2[Q * 8 + j];
        }
        svec8 bx;
        {
            const float4* px = (const float4*)(xcT + (size_t)b * 32 + Q * 8);
            float4 a = px[0], c = px[1];
            float iv[8] = {a.x,a.y,a.z,a.w,c.x,c.y,c.z,c.w};
            bx = pk8(iv);
        }
        fvec4 d0 = __builtin_amdgcn_mfma_f32_16x16x32_bf16(w1f0, bx, zc, 0,0,0);
        fvec4 d1 = __builtin_amdgcn_mfma_f32_16x16x32_bf16(w1f1, bx, zc, 0,0,0);
        float hv[8];
        #pragma unroll
        for (int j = 0; j < 4; j++) {
            hv[j]   = fmaxf(d0[j] + hb8[j], 0.f);
            hv[4+j] = fmaxf(d1[j] + hb8[4+j], 0.f);
        }
        svec8 hf = pk8(hv);
        fvec4 g0 = __builtin_amdgcn_mfma_f32_16x16x32_bf16(w2f0, hf, zc, 0,0,0);
        fvec4 g1 = __builtin_amdgcn_mfma_f32_16x16x32_bf16(w2f1, hf, zc, 0,0,0);
        if (tk == 11) {
            float xv[8];
            #pragma unroll
            for (int j = 0; j < 8; j++)
                xv[j] = (j < 4 ? g0[j] : g1[j - 4]) + xb8[j];
            *(svec8*)&XS[XSIDX(45, 11, Q * 8)] = pk8(xv);
        }
    }
    __syncthreads();

    // =================== GRAM: C = X^T X via mfma_32x32x16 ==============
    {
        const int feat = ln & 31, half = ln >> 5;
        fvec16 dG;
        #pragma unroll
        for (int i = 0; i < 16; i++) dG[i] = 0.f;
        for (int c = w; c < NTILE; c += NW) {
            svec8 af;
            #pragma unroll
            for (int j = 0; j < 8; j++)
                af[j] = (short)XS[XSIDX(c, half * 8 + j, feat)];
            dG = __builtin_amdgcn_mfma_f32_32x32x16_bf16(af, af, dG, 0, 0, 0);
        }
        #pragma unroll
        for (int rg = 0; rg < 16; rg++) {
            int row = (rg & 3) + 8 * (rg >> 2) + 4 * half;
            atomicAdd(&Cm[row * 32 + feat], dG[rg]);
        }
    }
    __syncthreads();

    // =================== ATTENTION COLLAPSE =============================
    for (int idx = tid; idx < 1024; idx += NTHR) {
        int i = idx >> 5, g = idx & 31;
        float a = 0.f;
        #pragma unroll
        for (int j = 0; j < 32; j++) a = fmaf(Cm[i * 32 + j], wk[g * 32 + j], a);
        T1f[i * 32 + g] = a;
    }
    __syncthreads();
    const float rsL = rsqrtf((float)LT);
    for (int idx = tid; idx < 1024; idx += NTHR) {
        int h = idx >> 5, g = idx & 31;
        float a = 0.f;
        #pragma unroll
        for (int i = 0; i < 32; i++) a = fmaf(wq[h * 32 + i], T1f[i * 32 + g], a);
        T2f[h * 32 + g] = a * rsL;
    }
    __syncthreads();
    if (tid < 32) {
        float mx = -1e30f;
        #pragma unroll
        for (int g = 0; g < 32; g++) mx = fmaxf(mx, T2f[tid * 32 + g]);
        float s = 0.f;
        #pragma unroll
        for (int g = 0; g < 32; g++) {
            float e = __expf(T2f[tid * 32 + g] - mx);
            T2f[tid * 32 + g] = e; s += e;
        }
        float inv = 1.f / s;
        #pragma unroll
        for (int g = 0; g < 32; g++) T2f[tid * 32 + g] *= inv;
    }
    __syncthreads();
    for (int idx = tid; idx < 1024; idx += NTHR) {
        int h = idx >> 5, j = idx & 31;
        float a = 0.f;
        #pragma unroll
        for (int g = 0; g < 32; g++) a = fmaf(T2f[h * 32 + g], wv[g * 32 + j], a);
        T1f[h * 32 + j] = a;
    }
    __syncthreads();
    for (int idx = tid; idx < 1024; idx += NTHR) {
        int o = idx >> 5, j = idx & 31;
        float a = 0.f;
        #pragma unroll
        for (int h = 0; h < 32; h++) a = fmaf(wo[o * 32 + h], T1f[h * 32 + j], a);
        Wbb[o * 32 + j] = f2bf(a + (o == j ? 1.f : 0.f));    // Wb + I
    }
    __syncthreads();

    // =================== PIPELINE: register-chained MFMAs ===============
    svec8 wbf0 = *(const svec8*)&Wbb[Lr0 * 32 + Q * 8];
    svec8 wbf1 = *(const svec8*)&Wbb[Lr1 * 32 + Q * 8];
    svec8 a1f0, a1f1, a2f0, a2f1, a3f0, a3f1;
    #pragma unroll
    for (int j = 0; j < 8; j++) {
        a1f0[j] = (short)f2bf(f1w1[Lr0 * 32 + Q * 8 + j]);
        a1f1[j] = (short)f2bf(f1w1[Lr1 * 32 + Q * 8 + j]);
        a2f0[j] = (short)f2bf(f1w2[Lr0 * 32 + Q * 8 + j]);
        a2f1[j] = (short)f2bf(f1w2[Lr1 * 32 + Q * 8 + j]);
        a3f0[j] = (short)f2bf(f2w1[Lr0 * 32 + Q * 8 + j]);
        a3f1[j] = (short)f2bf(f2w1[Lr1 * 32 + Q * 8 + j]);
    }
    unsigned pg1[4], pb1[4], pg2[4], pb2[4], pc1[4], pc2[4], pc3[4], pw2[4];
    #pragma unroll
    for (int i = 0; i < 4; i++) {
        int f = Q * 8 + 2 * i;
        pg1[i] = pk2(ln1g[f], ln1g[f + 1]);
        pb1[i] = pk2(ln1b[f], ln1b[f + 1]);
        pg2[i] = pk2(ln2g[f], ln2g[f + 1]);
        pb2[i] = pk2(ln2b[f], ln2b[f + 1]);
        pc1[i] = pk2(f1b1[f], f1b1[f + 1]);
        pc2[i] = pk2(f1b2[f], f1b2[f + 1]);
        pc3[i] = pk2(f2b1[f], f2b1[f + 1]);
        pw2[i] = pk2(f2w2[f], f2w2[f + 1]);
    }
    const float ybias = f2b2[0];

    float s0 = 0.f, s1 = 0.f, s2 = 0.f;
    for (int t = w; t < NTILE; t += NW) {
        union { svec8 s; unsigned short us[8]; } xr;
        xr.s = *(const svec8*)&XS[XSIDX(t, tk, Q * 8)];     // one b128: frag + residual
        svec8 bx = xr.s;
        float xf[8];
        #pragma unroll
        for (int j = 0; j < 8; j++) xf[j] = bf2f(xr.us[j]);

        fvec4 d0 = __builtin_amdgcn_mfma_f32_16x16x32_bf16(wbf0, bx, zc, 0,0,0);
        fvec4 d1 = __builtin_amdgcn_mfma_f32_16x16x32_bf16(wbf1, bx, zc, 0,0,0);
        float v[8];
        #pragma unroll
        for (int j = 0; j < 4; j++) { v[j] = d0[j]; v[4 + j] = d1[j]; }
        float S = 0.f;
        #pragma unroll
        for (int j = 0; j < 8; j++) S += v[j];
        S += __shfl_xor(S, 16); S += __shfl_xor(S, 32);
        float mean = S * (1.f / 32.f);
        float vs = 0.f;
        #pragma unroll
        for (int j = 0; j < 8; j++) { float d = v[j] - mean; vs = fmaf(d, d, vs); }
        vs += __shfl_xor(vs, 16); vs += __shfl_xor(vs, 32);
        float rs = rsqrtf(vs * (1.f / 32.f) + 1e-5f);
        float tv[8];
        #pragma unroll
        for (int j = 0; j < 8; j++)
            tv[j] = (v[j] - mean) * rs * pget(pg1, j) + pget(pb1, j);
        svec8 tf = pk8(tv);
        fvec4 u0 = __builtin_amdgcn_mfma_f32_16x16x32_bf16(a1f0, tf, zc, 0,0,0);
        fvec4 u1 = __builtin_amdgcn_mfma_f32_16x16x32_bf16(a1f1, tf, zc, 0,0,0);
        float uv[8];
        #pragma unroll
        for (int j = 0; j < 4; j++) {
            uv[j]   = fmaxf(u0[j] + pget(pc1, j), 0.f);
            uv[4+j] = fmaxf(u1[j] + pget(pc1, 4 + j), 0.f);
        }
        svec8 uf = pk8(uv);
        fvec4 g0 = __builtin_amdgcn_mfma_f32_16x16x32_bf16(a2f0, uf, zc, 0,0,0);
        fvec4 g1 = __builtin_amdgcn_mfma_f32_16x16x32_bf16(a2f1, uf, zc, 0,0,0);
        #pragma unroll
        for (int j = 0; j < 8; j++)
            v[j] = (j < 4 ? g0[j] : g1[j - 4]) + pget(pc2, j) + xf[j];
        float S2 = 0.f;
        #pragma unroll
        for (int j = 0; j < 8; j++) S2 += v[j];
        S2 += __shfl_xor(S2, 16); S2 += __shfl_xor(S2, 32);
        float mean2 = S2 * (1.f / 32.f);
        float vs2 = 0.f;
        #pragma unroll
        for (int j = 0; j < 8; j++) { float d = v[j] - mean2; vs2 = fmaf(d, d, vs2); }
        vs2 += __shfl_xor(vs2, 16); vs2 += __shfl_xor(vs2, 32);
        float rs2 = rsqrtf(vs2 * (1.f / 32.f) + 1e-5f);
        #pragma unroll
        for (int j = 0; j < 8; j++)
            tv[j] = (v[j] - mean2) * rs2 * pget(pg2, j) + pget(pb2, j);
        svec8 t2 = pk8(tv);
        fvec4 e0 = __builtin_amdgcn_mfma_f32_16x16x32_bf16(a3f0, t2, zc, 0,0,0);
        fvec4 e1 = __builtin_amdgcn_mfma_f32_16x16x32_bf16(a3f1, t2, zc, 0,0,0);
        float yp = 0.f;
        #pragma unroll
        for (int j = 0; j < 8; j++) {
            float e = (j < 4 ? e0[j] : e1[j - 4]) + pget(pc3, j);
            yp = fmaf(pget(pw2, j), fmaxf(e, 0.f), yp);
        }
        yp += __shfl_xor(yp, 16); yp += __shfl_xor(yp, 32);
        if (Q == 0) {
            int tok = t * 16 + tk;
            float yv = yp + ybias;
            if (tok < L0T)            s0 += yv;
            else if (tok < LT - 1)    s1 += yv;
            else if (tok == LT - 1)   s2 += yv;
        }
    }

    s0 += __shfl_xor(s0, 1); s0 += __shfl_xor(s0, 2);
    s0 += __shfl_xor(s0, 4); s0 += __shfl_xor(s0, 8);
    s1 += __shfl_xor(s1, 1); s1 += __shfl_xor(s1, 2);
    s1 += __shfl_xor(s1, 4); s1 += __shfl_xor(s1, 8);
    s2 += __shfl_xor(s2, 1); s2 += __shfl_xor(s2, 2);
    s2 += __shfl_xor(s2, 4); s2 += __shfl_xor(s2, 8);
    if (ln == 0) { red[w * 3] = s0; red[w * 3 + 1] = s1; red[w * 3 + 2] = s2; }
    __syncthreads();
    if (tid == 0) {
        float a0 = 0.f, a1 = 0.f, a2 = 0.f;
        #pragma unroll
        for (int k = 0; k < NW; k++) {
            a0 += red[k * 3]; a1 += red[k * 3 + 1]; a2 += red[k * 3 + 2];
        }
        out[b] = a0 / (float)L0T + a1 / (float)L1T + a2;
    }
}

extern "C" void kernel_launch(void* const* d_in, const int* in_sizes, int n_in,
                              void* d_out, int out_size, void* d_ws, size_t ws_size,
                              hipStream_t stream)
{
    const float* x0   = (const float*)d_in[0];
    const float* x1   = (const float*)d_in[1];
    const float* pos0 = (const float*)d_in[2];
    const float* pos1 = (const float*)d_in[3];
    const float* xcT  = (const float*)d_in[4];
    const float* e0w1 = (const float*)d_in[5];
    const float* e0b1 = (const float*)d_in[6];
    const float* e0w2 = (const float*)d_in[7];
    const float* e0b2 = (const float*)d_in[8];
    const float* e1w1 = (const float*)d_in[9];
    const float* e1b1 = (const float*)d_in[10];
    const float* e1w2 = (const float*)d_in[11];
    const float* e1b2 = (const float*)d_in[12];
    const float* ecw1 = (const float*)d_in[13];
    const float* ecb1 = (const float*)d_in[14];
    const float* ecw2 = (const float*)d_in[15];
    const float* ecb2 = (const float*)d_in[16];
    const float* wq   = (const float*)d_in[17];
    const float* wk   = (const float*)d_in[18];
    const float* wv   = (const float*)d_in[19];
    const float* wo   = (const float*)d_in[20];
    const float* ln1g = (const float*)d_in[21];
    const float* ln1b = (const float*)d_in[22];
    const float* ln2g = (const float*)d_in[23];
    const float* ln2b = (const float*)d_in[24];
    const float* f1w1 = (const float*)d_in[25];
    const float* f1b1 = (const float*)d_in[26];
    const float* f1w2 = (const float*)d_in[27];
    const float* f1b2 = (const float*)d_in[28];
    const float* f2w1 = (const float*)d_in[29];
    const float* f2b1 = (const float*)d_in[30];
    const float* f2w2 = (const float*)d_in[31];
    const float* f2b2 = (const float*)d_in[32];
    float* out = (float*)d_out;

    const int B = in_sizes[0] / (L0T * 8);

    hipLaunchKernelGGL(fused_kernel, dim3(B), dim3(NTHR), 0, stream,
                       x0, x1, pos0, pos1, xcT,
                       e0w1, e0b1, e0w2, e0b2, e1w1, e1b1, e1w2, e1b2,
                       ecw1, ecb1, ecw2, ecb2, wq, wk, wv, wo,
                       ln1g, ln1b, ln2g, ln2b,
                       f1w1, f1b1, f1w2, f1b2, f2w1, f2b1, f2w2, f2b2,
                       out);
}